// Round 8
// baseline (145.162 us; speedup 1.0000x reference)
//
#include <hip/hip_runtime.h>

#define DIM     1024
#define BATCH   512
#define OUTD    5377
#define NHEADS  10
#define NLAYERS 5
#define LDK     72   // padded bf16 leading dim for MLP tiles

typedef __attribute__((ext_vector_type(4))) float f32x4;
typedef __attribute__((ext_vector_type(8))) short bf16x8;

__device__ __forceinline__ unsigned short f2bf(float f) {
    unsigned u = __builtin_bit_cast(unsigned, f);
    u = (u + 0x7FFFu + ((u >> 16) & 1u)) >> 16;
    return (unsigned short)u;
}
__device__ __forceinline__ float bf2f(unsigned short h) {
    unsigned u = ((unsigned)h) << 16;
    return __builtin_bit_cast(float, u);
}
__device__ __forceinline__ unsigned pk2(float a, float b) {
    return (unsigned)f2bf(a) | ((unsigned)f2bf(b) << 16);
}
__device__ __forceinline__ void gload16(const void* g, void* l) {
    __builtin_amdgcn_global_load_lds(
        (const __attribute__((address_space(1))) unsigned int*)g,
        (__attribute__((address_space(3))) unsigned int*)l,
        16, 0, 0);
}

// ---------------- grouping: bucket batches by rule_len ----------------
__global__ void group_kernel(const int* __restrict__ rule_len,
                             int* __restrict__ bidx,
                             int* __restrict__ gstart,
                             int* __restrict__ gcount) {
    __shared__ int s_count[NHEADS];
    __shared__ int s_fill[NHEADS];
    int t = threadIdx.x;
    if (t < NHEADS) s_count[t] = 0;
    __syncthreads();
    int h = rule_len[t];
    atomicAdd(&s_count[h], 1);
    __syncthreads();
    if (t == 0) {
        int acc = 0;
        for (int i = 0; i < NHEADS; ++i) {
            gstart[i] = acc;
            gcount[i] = s_count[i];
            s_fill[i] = acc;
            acc += s_count[i];
        }
    }
    __syncthreads();
    int pos = atomicAdd(&s_fill[h], 1);
    bidx[pos] = t;
}

// ---------------- latent f32 -> bf16 ----------------
__global__ void convert_latent(const float* __restrict__ in,
                               unsigned short* __restrict__ out) {
    int i = blockIdx.x * blockDim.x + threadIdx.x;   // one float4 per thread
    float4 v = ((const float4*)in)[i];
    ushort4 o;
    o.x = f2bf(v.x); o.y = f2bf(v.y); o.z = f2bf(v.z); o.w = f2bf(v.w);
    ((ushort4*)out)[i] = o;
}

// ---------------- MLP layer: C = A @ W^T + bias  (MFMA, W hi/lo, pipelined) --
__global__ __launch_bounds__(256) void mlp_mfma(
    const unsigned short* __restrict__ A,
    const float* __restrict__ W,
    const float* __restrict__ bias,
    unsigned short* __restrict__ C)
{
    __shared__ __align__(16) unsigned short As[2][32][LDK];
    __shared__ __align__(16) unsigned short Whi[2][32][LDK];
    __shared__ __align__(16) unsigned short Wlo[2][32][LDK];

    const int tid = threadIdx.x;
    const int n0 = blockIdx.x * 32;
    const int m0 = blockIdx.y * 32;
    const int lane = tid & 63;
    const int wid = tid >> 6;
    const int wm = (wid >> 1) * 16;
    const int wn = (wid & 1) * 16;

    f32x4 acc = {0.f, 0.f, 0.f, 0.f};

    const int ar = tid >> 3;          // 0..31
    const int ac = (tid & 7) * 8;     // 0..56 bf16 units
    const int wr = tid >> 4;          // 0..15
    const int wc = (tid & 15) * 4;    // 0..60 f32 units

    const unsigned short* Ap = A + (size_t)(m0 + ar) * DIM + ac;
    const float* Wp0 = W + (size_t)(n0 + wr) * DIM + wc;
    const float* Wp1 = W + (size_t)(n0 + wr + 16) * DIM + wc;

    uint4  ra  = *(const uint4*)(Ap);
    float4 rw0 = *(const float4*)(Wp0);
    float4 rw1 = *(const float4*)(Wp1);

    for (int t = 0; t < DIM / 64; ++t) {
        const int cur = t & 1;
        *(uint4*)&As[cur][ar][ac] = ra;
        {
            ushort4 hi, lo;
            hi.x = f2bf(rw0.x); lo.x = f2bf(rw0.x - bf2f(hi.x));
            hi.y = f2bf(rw0.y); lo.y = f2bf(rw0.y - bf2f(hi.y));
            hi.z = f2bf(rw0.z); lo.z = f2bf(rw0.z - bf2f(hi.z));
            hi.w = f2bf(rw0.w); lo.w = f2bf(rw0.w - bf2f(hi.w));
            *(ushort4*)&Whi[cur][wr][wc] = hi;
            *(ushort4*)&Wlo[cur][wr][wc] = lo;
            hi.x = f2bf(rw1.x); lo.x = f2bf(rw1.x - bf2f(hi.x));
            hi.y = f2bf(rw1.y); lo.y = f2bf(rw1.y - bf2f(hi.y));
            hi.z = f2bf(rw1.z); lo.z = f2bf(rw1.z - bf2f(hi.z));
            hi.w = f2bf(rw1.w); lo.w = f2bf(rw1.w - bf2f(hi.w));
            *(ushort4*)&Whi[cur][wr + 16][wc] = hi;
            *(ushort4*)&Wlo[cur][wr + 16][wc] = lo;
        }
        __syncthreads();
        if (t < DIM / 64 - 1) {
            const int k0 = (t + 1) * 64;
            ra  = *(const uint4*)(Ap + k0);
            rw0 = *(const float4*)(Wp0 + k0);
            rw1 = *(const float4*)(Wp1 + k0);
        }
        #pragma unroll
        for (int kk = 0; kk < 2; ++kk) {
            const int ko = kk * 32 + (lane >> 4) * 8;
            bf16x8 a  = *(const bf16x8*)&As[cur][wm + (lane & 15)][ko];
            bf16x8 bh = *(const bf16x8*)&Whi[cur][wn + (lane & 15)][ko];
            bf16x8 bl = *(const bf16x8*)&Wlo[cur][wn + (lane & 15)][ko];
            acc = __builtin_amdgcn_mfma_f32_16x16x32_bf16(a, bh, acc, 0, 0, 0);
            acc = __builtin_amdgcn_mfma_f32_16x16x32_bf16(a, bl, acc, 0, 0, 0);
        }
    }

    const int cn = n0 + wn + (lane & 15);
    const float bn = bias[cn];
    const int rbase = m0 + wm + (lane >> 4) * 4;
    #pragma unroll
    for (int j = 0; j < 4; ++j) {
        C[(size_t)(rbase + j) * DIM + cn] = f2bf(acc[j] + bn);
    }
}

// ------- head: wave-private W staging, zero barriers, FIFO vmcnt pipeline ----
// Each wave owns 16 W rows. W staged f32 into wave-private LDS dbuf via
// global_load_lds (inverse-swizzled per-lane source, linear dest, swizzled
// read). A fragments via asm global loads, single-slotted (32 VGPR).
// FIFO invariant at each wait: outstanding = [W(t):4][A(t):8][W(t+1):4];
// vmcnt(4) retires W(t)+A(t). sched_barrier(0) pins every segment boundary.
__global__ __launch_bounds__(256, 3) void head_wp(
    const unsigned short* __restrict__ H,   // BATCH x DIM bf16
    const float* __restrict__ Wh,           // NHEADS x OUTD x DIM f32
    const float* __restrict__ bh,           // NHEADS x OUTD f32
    const int* __restrict__ bidx,
    const int* __restrict__ gstart,
    const int* __restrict__ gcount,
    float* __restrict__ out)                // BATCH x OUTD f32
{
    const int head = blockIdx.z;
    const int cnt  = gcount[head];
    const int m0   = blockIdx.y * 64;
    if (m0 >= cnt) return;
    const int start = gstart[head];

    __shared__ __align__(16) char Wl[4][2][4096];   // 32 KB: [wave][buf][16 rows x 256B]

    const int tid  = threadIdx.x;
    const int lane = tid & 63;
    const int wv   = tid >> 6;
    const int col  = lane & 15;
    const int hk   = lane >> 4;

    const int n0w = (blockIdx.x * 4 + wv) * 16;

    // W sources: instr p covers rows rp = p*4+hk; 16B unit index = col,
    // pre-swizzled (col ^ (rp&7)) so the swizzled LDS read is conflict-free.
    const float* WhL = Wh + (size_t)head * OUTD * DIM;
    const char* gW[4];
    #pragma unroll
    for (int p = 0; p < 4; ++p) {
        int rp = p * 4 + hk;
        int grow = n0w + rp; if (grow > OUTD - 1) grow = OUTD - 1;
        gW[p] = (const char*)(WhL + (size_t)grow * DIM) + ((col ^ (rp & 7)) << 4);
    }
    // A bases: lane's A row = m0 + mf*16 + col (clamped), k byte offset hk*16
    const char* Abp[4];
    #pragma unroll
    for (int mf = 0; mf < 4; ++mf) {
        int m = m0 + mf * 16 + col; if (m > cnt - 1) m = cnt - 1;
        Abp[mf] = (const char*)(H + (size_t)bidx[start + m] * DIM) + hk * 16;
    }

    char* myL = &Wl[wv][0][0];
    uint4 pa[4][2];          // single-slot A prefetch (32 VGPR)
    f32x4 acc[4] = {};

    auto stageW = [&](int buf, int t) {
        #pragma unroll
        for (int p = 0; p < 4; ++p)
            gload16(gW[p] + t * 256, myL + buf * 4096 + p * 1024 + lane * 16);
    };
    auto loadA = [&](int t) {
        #pragma unroll
        for (int mf = 0; mf < 4; ++mf) {
            #pragma unroll
            for (int ks = 0; ks < 2; ++ks) {
                asm volatile("global_load_dwordx4 %0, %1, off"
                             : "=v"(pa[mf][ks])
                             : "v"(Abp[mf] + t * 128 + ks * 64));
            }
        }
    };
    auto compute = [&](int buf) {
        const char* br = myL + buf * 4096 + col * 256;
        #pragma unroll
        for (int ks = 0; ks < 2; ++ks) {
            const int u0 = ks * 8 + hk * 2;
            f32x4 w0 = *(const f32x4*)(br + (((u0    ) ^ (col & 7)) << 4));
            f32x4 w1 = *(const f32x4*)(br + (((u0 + 1) ^ (col & 7)) << 4));
            uint4 wk;
            wk.x = pk2(w0.x, w0.y); wk.y = pk2(w0.z, w0.w);
            wk.z = pk2(w1.x, w1.y); wk.w = pk2(w1.z, w1.w);
            bf16x8 wf = __builtin_bit_cast(bf16x8, wk);
            #pragma unroll
            for (int mf = 0; mf < 4; ++mf) {
                bf16x8 a = __builtin_bit_cast(bf16x8, pa[mf][ks]);
                acc[mf] = __builtin_amdgcn_mfma_f32_16x16x32_bf16(a, wf, acc[mf], 0, 0, 0);
            }
        }
    };

    // prologue FIFO: [W0:4][A0:8][W1:4] = 16 outstanding
    stageW(0, 0);
    __builtin_amdgcn_sched_barrier(0);
    loadA(0);
    __builtin_amdgcn_sched_barrier(0);
    stageW(1, 1);
    __builtin_amdgcn_sched_barrier(0);

    #pragma unroll
    for (int t = 0; t < 14; ++t) {
        asm volatile("s_waitcnt vmcnt(4)" ::: "memory");  // W(t)+A(t) done; W(t+1) in flight
        __builtin_amdgcn_sched_barrier(0);
        compute(t & 1);
        __builtin_amdgcn_sched_barrier(0);
        loadA(t + 1);
        __builtin_amdgcn_sched_barrier(0);
        stageW(t & 1, t + 2);
        __builtin_amdgcn_sched_barrier(0);
    }
    // t = 14
    asm volatile("s_waitcnt vmcnt(4)" ::: "memory");
    __builtin_amdgcn_sched_barrier(0);
    compute(0);
    __builtin_amdgcn_sched_barrier(0);
    loadA(15);
    __builtin_amdgcn_sched_barrier(0);
    // t = 15
    asm volatile("s_waitcnt vmcnt(0)" ::: "memory");
    __builtin_amdgcn_sched_barrier(0);
    compute(1);

    const int n = n0w + col;
    if (n < OUTD) {
        const float bn = bh[(size_t)head * OUTD + n];
        #pragma unroll
        for (int mf = 0; mf < 4; ++mf) {
            #pragma unroll
            for (int j = 0; j < 4; ++j) {
                int row = m0 + mf * 16 + hk * 4 + j;
                if (row < cnt) {
                    int b = bidx[start + row];
                    out[(size_t)b * OUTD + n] = acc[mf][j] + bn;
                }
            }
        }
    }
}

extern "C" void kernel_launch(void* const* d_in, const int* in_sizes, int n_in,
                              void* d_out, int out_size, void* d_ws, size_t ws_size,
                              hipStream_t stream) {
    const float* latent   = (const float*)d_in[0];
    const float* W_mlp    = (const float*)d_in[1];
    const float* b_mlp    = (const float*)d_in[2];
    const float* W_heads  = (const float*)d_in[3];
    const float* b_heads  = (const float*)d_in[4];
    const int*   rule_len = (const int*)d_in[5];
    float* out = (float*)d_out;

    unsigned short* h0 = (unsigned short*)d_ws;
    unsigned short* h1 = h0 + (size_t)BATCH * DIM;
    int* bidx   = (int*)(h1 + (size_t)BATCH * DIM);
    int* gstart = bidx + BATCH;
    int* gcount = gstart + 16;

    group_kernel<<<1, BATCH, 0, stream>>>(rule_len, bidx, gstart, gcount);
    convert_latent<<<(BATCH * DIM / 4) / 256, 256, 0, stream>>>(latent, h0);

    dim3 mgrid(DIM / 32, BATCH / 32);
    const unsigned short* src = h0;
    unsigned short* dst = h1;
    for (int l = 0; l < NLAYERS; ++l) {
        mlp_mfma<<<mgrid, 256, 0, stream>>>(src,
                                            W_mlp + (size_t)l * DIM * DIM,
                                            b_mlp + (size_t)l * DIM,
                                            dst);
        unsigned short* t = (unsigned short*)src;
        src = dst;
        dst = t;
    }

    // x: 85 n-chunks of 64 (4 waves x 16 rows); y: 2 m-chunks of 64
    dim3 hgrid((OUTD + 63) / 64, 2, NHEADS);
    head_wp<<<hgrid, 256, 0, stream>>>(src, W_heads, b_heads,
                                       bidx, gstart, gcount, out);
}